// Round 9
// baseline (194.866 us; speedup 1.0000x reference)
//
#include <hip/hip_runtime.h>
#include <math.h>

#define FMPX 40
#define NPOS 1600          // 40*40
#define NCLS 80
#define NBOX 8000
#define KDIM 512
#define CAP  256           // per-class candidate capacity (mean ~100/class, +15 sigma)

// anchor (w,h) pairs
__constant__ float c_aw[5] = {17.f, 55.f, 92.f, 202.f, 289.f};
__constant__ float c_ah[5] = {25.f, 75.f, 206.f, 21.f, 311.f};

__device__ __forceinline__ float sigf(float x) { return 1.0f / (1.0f + expf(-x)); }
__device__ __forceinline__ float rlanef(float v, int lane) {
    return __uint_as_float(__builtin_amdgcn_readlane(__float_as_uint(v), lane));
}

// A-prefetch helpers (16 k-values, 2 positions)
__device__ __forceinline__ void loadA(float (&Ba)[16], float (&Bb)[16],
                                      const float* __restrict__ apa,
                                      const float* __restrict__ apb, int kbase) {
#pragma unroll
    for (int t = 0; t < 16; t++) {
        Ba[t] = apa[(kbase + t) * NPOS];
        Bb[t] = apb[(kbase + t) * NPOS];
    }
}
// per-acc FMA order: k ascending within the 16-block; j-interleave doesn't
// affect per-accumulator order -> bitwise-identical to R1-R8 sums.
__device__ __forceinline__ void consumeA(const float (&Ba)[16], const float (&Bb)[16],
                                         const float* __restrict__ Ws, int kk,
                                         float (&acc)[4], float (&acd)[4]) {
#pragma unroll
    for (int j = 0; j < 4; j++) {
        const float* wp = &Ws[j * KDIM + kk];
#pragma unroll
        for (int t = 0; t < 16; t++) {
            acc[j] += Ba[t] * wp[t];
            acd[j] += Bb[t] * wp[t];
        }
    }
}

// ---------------------------------------------------------------------------
// K1: the three 1x1-conv GEMMs. M=128/wave (2 pos/lane), single-wave blocks,
// W tile 4 rows = 8KB LDS (broadcast ds_read_b128; scalar pipe for per-step W
// is DEAD: R4/R6 77/81us). R8 lesson: 5.4 waves/CU can't hide ~700cyc A-load
// latency with 16-24k prefetch -> R9 triple-buffers A 48k ahead (~2 full
// 16k-steps ~ 700cyc). LDS floor ~14us/CU.
// grid = (13 M-tiles of 128 pos, 107 N-tiles of 4 outs); block (0,0) also
// zeroes counts[] for k_box's atomic list build (kernel-boundary ordered).
// Per-acc FMA order strictly ascending k — bitwise-identical to R1-R8
// (absmax stable at 2.0 across all rounds).
// ---------------------------------------------------------------------------
__global__ __launch_bounds__(64) void k_gemm(
    const float* __restrict__ cls_feat, const float* __restrict__ reg_feat,
    const float* __restrict__ w_obj, const float* __restrict__ b_obj,
    const float* __restrict__ w_cls, const float* __restrict__ b_cls,
    const float* __restrict__ w_reg, const float* __restrict__ b_reg,
    float* __restrict__ clsRaw,   // [1600][400]
    float* __restrict__ roRaw,    // [1600][25]: 0..4 obj, 5..24 reg
    int* __restrict__ counts)     // [80] zeroed here for k_box
{
    __shared__ float Ws[4 * KDIM];         // 8 KB
    const int mTile = blockIdx.x;          // 0..12
    const int nTile = blockIdx.y;          // 0..106
    const int hw0   = mTile * 128;
    const bool isCls = (nTile < 100);
    const float* feat = isCls ? cls_feat : reg_feat;
    const int lane = threadIdx.x;
    const int oBase = isCls ? nTile * 4 : (nTile - 100) * 4;

    if (mTile == 0 && nTile == 0) {
        counts[lane] = 0;                       // lanes 0..63
        if (lane < NCLS - 64) counts[64 + lane] = 0;
    }

    // two positions per lane; pos1 invalid only in the last partial M-tile
    const bool ok1 = (hw0 + 64 + lane) < NPOS;
    const float* apa = feat + hw0 + lane;
    const float* apb = feat + (ok1 ? hw0 + 64 + lane : hw0 + lane);

    // A triple buffer: 48k in flight
    float B0a[16], B0b[16], B1a[16], B1b[16], B2a[16], B2b[16];
    loadA(B0a, B0b, apa, apb, 0);
    loadA(B1a, B1b, apa, apb, 16);
    loadA(B2a, B2b, apa, apb, 32);

    // ---- stage W tile [4][512] (8 float4 per lane, coalesced) ----
    for (int i = lane * 4; i < 4 * KDIM; i += 64 * 4) {
        int r = i >> 9, k = i & 511;
        const float* src;
        bool valid = true;
        if (isCls) {
            src = w_cls + (oBase + r) * KDIM + k;
        } else {
            int o = oBase + r;
            if (o < 5)       src = w_obj + o * KDIM + k;
            else if (o < 25) src = w_reg + (o - 5) * KDIM + k;
            else           { src = w_obj; valid = false; }
        }
        float4 v = valid ? *(const float4*)src : make_float4(0.f, 0.f, 0.f, 0.f);
        *(float4*)&Ws[i] = v;
    }

    float bias[4];
    bool ok[4];
#pragma unroll
    for (int j = 0; j < 4; j++) {
        int o = oBase + j;
        if (isCls)      { bias[j] = b_cls[o];     ok[j] = true; }
        else if (o < 5) { bias[j] = b_obj[o];     ok[j] = true; }
        else if (o < 25){ bias[j] = b_reg[o - 5]; ok[j] = true; }
        else            { bias[j] = 0.0f;         ok[j] = false; }
    }

    __syncthreads();

    float acc[4] = {0.f, 0.f, 0.f, 0.f};
    float acd[4] = {0.f, 0.f, 0.f, 0.f};

    // main loop: kk = 0,48,...,384 consumes k=0..431, refills 48..479
    int kk = 0;
    for (; kk + 96 <= KDIM; kk += 48) {
        consumeA(B0a, B0b, Ws, kk,      acc, acd);  loadA(B0a, B0b, apa, apb, kk + 48);
        consumeA(B1a, B1b, Ws, kk + 16, acc, acd);  loadA(B1a, B1b, apa, apb, kk + 64);
        consumeA(B2a, B2b, Ws, kk + 32, acc, acd);  loadA(B2a, B2b, apa, apb, kk + 80);
    }
    // epilogue: kk == 432; remaining k = 432..511
    consumeA(B0a, B0b, Ws, 432, acc, acd);  loadA(B0a, B0b, apa, apb, 480);
    consumeA(B1a, B1b, Ws, 448, acc, acd);  loadA(B1a, B1b, apa, apb, 496);
    consumeA(B2a, B2b, Ws, 464, acc, acd);
    consumeA(B0a, B0b, Ws, 480, acc, acd);
    consumeA(B1a, B1b, Ws, 496, acc, acd);

    const int hw  = hw0 + lane;
    const int hw2 = hw + 64;
    if (isCls) {
        float4 r0 = make_float4(acc[0] + bias[0], acc[1] + bias[1],
                                acc[2] + bias[2], acc[3] + bias[3]);
        *(float4*)&clsRaw[hw * 400 + oBase] = r0;
        if (ok1) {
            float4 r1 = make_float4(acd[0] + bias[0], acd[1] + bias[1],
                                    acd[2] + bias[2], acd[3] + bias[3]);
            *(float4*)&clsRaw[hw2 * 400 + oBase] = r1;
        }
    } else {
#pragma unroll
        for (int j = 0; j < 4; j++) {
            int o = oBase + j;
            if (ok[j]) {
                roRaw[hw * 25 + o] = acc[j] + bias[j];
                if (ok1) roRaw[hw2 * 25 + o] = acd[j] + bias[j];
            }
        }
    }
}

// ---------------------------------------------------------------------------
// K2: per-box scores, argmax label, decode, outputs, AND per-class candidate
// append (one global atomicAdd per box on lane 0; compaction order is
// irrelevant — k_nms's sort by (score desc, idx asc) is deterministic ==
// stable argsort(-score) restricted to the class).
// 2000 blocks x 256 thr; each of the 4 waves handles one box.
// ---------------------------------------------------------------------------
__global__ __launch_bounds__(256) void k_box(
    const float* __restrict__ clsRaw, const float* __restrict__ roRaw,
    float* __restrict__ out,          // d_out: [32000 bboxes][8000 score][8000 labels][8000 keep]
    float4* __restrict__ nmsBox, float* __restrict__ nmsArea,
    float* __restrict__ listScore, int* __restrict__ listIdx, int* __restrict__ counts)
{
    const int n = blockIdx.x * 4 + (threadIdx.x >> 6);   // box index 0..7999
    const int lane = threadIdx.x & 63;
    const int hw = n / 5, a = n % 5;

    const float sobj = sigf(roRaw[hw * 25 + a]);
    const float* cbase = clsRaw + hw * 400 + a * 80;

    const int l4 = (lane < 20) ? lane : 19;     // clamp for safe address
    float4 cs = *(const float4*)(cbase + l4 * 4);

    // in-lane first-max over classes l4*4..l4*4+3 (strict > keeps first)
    float s0 = sqrtf(sobj * sigf(cs.x));
    float s1 = sqrtf(sobj * sigf(cs.y));
    float s2 = sqrtf(sobj * sigf(cs.z));
    float s3 = sqrtf(sobj * sigf(cs.w));
    float v = s0; int bi = l4 * 4;
    if (s1 > v) { v = s1; bi = l4 * 4 + 1; }
    if (s2 > v) { v = s2; bi = l4 * 4 + 2; }
    if (s3 > v) { v = s3; bi = l4 * 4 + 3; }
    if (lane >= 20) { v = -1.0f; bi = 0x7FFFFFFF; }  // scores are always > 0

    // cross-lane: max score, ties -> lowest class (== jnp.argmax first-max)
#pragma unroll
    for (int off = 32; off >= 1; off >>= 1) {
        float ov = __shfl_xor(v, off);
        int   oi = __shfl_xor(bi, off);
        if (ov > v || (ov == v && oi < bi)) { v = ov; bi = oi; }
    }

    if (lane == 0) {
        const float* rp = roRaw + hw * 25 + 5 + a * 4;
        float r0 = rp[0], r1 = rp[1], r2 = rp[2], r3 = rp[3];
        float gx = (float)(hw % FMPX), gy = (float)(hw / FMPX);
        float cx = (sigf(r0) + gx) * 32.0f;
        float cy = (sigf(r1) + gy) * 32.0f;
        float wv = expf(r2) * c_aw[a];
        float hv = expf(r3) * c_ah[a];
        float x1 = cx - wv * 0.5f, y1 = cy - hv * 0.5f;
        float x2 = cx + wv * 0.5f, y2 = cy + hv * 0.5f;

        *(float4*)&out[n * 4] = make_float4(x1, y1, x2, y2);
        out[32000 + n] = v;
        out[40000 + n] = (float)bi;
        out[48000 + n] = 0.0f;            // keep init (k_nms sets 1s later)

        // b2: reinterpret x1y1x2y2 as cxcywh (faithful to the reference nms())
        float nx1 = x1 - x2 * 0.5f, ny1 = y1 - y2 * 0.5f;
        float nx2 = x1 + x2 * 0.5f, ny2 = y1 + y2 * 0.5f;
        nmsBox[n]  = make_float4(nx1, ny1, nx2, ny2);
        nmsArea[n] = (nx2 - nx1) * (ny2 - ny1);

        if (v >= 0.3f) {
            int p = atomicAdd(&counts[bi], 1);
            if (p < CAP) { listScore[bi * CAP + p] = v; listIdx[bi * CAP + p] = n; }
        }
    }
}

// ---------------------------------------------------------------------------
// K3: per-class greedy NMS — one wave per class, NO 64KB scan (R8 lesson:
// the compiler kept 1 scan load in flight -> ~60us of serial latency; the
// candidate list is now pre-compacted by k_box). Load <=4 entries/lane,
// bitonic sort by (score desc, idx asc), register-resident greedy with
// v_readlane broadcasts (R8 structure), scatter keep bits.
// ---------------------------------------------------------------------------
__global__ __launch_bounds__(64) void k_nms(
    const float* __restrict__ listScore, const int* __restrict__ listIdx,
    const int* __restrict__ counts,
    const float4* __restrict__ nmsBox, const float* __restrict__ nmsArea,
    float* __restrict__ keepOut)
{
    const int c = blockIdx.x;
    const int lane = threadIdx.x;

    __shared__ float ss[CAP];
    __shared__ int   si[CAP];

    int m = counts[c];
    if (m > CAP) m = CAP;

    int P = 2;
    while (P < m) P <<= 1;
    for (int i = lane; i < P; i += 64) {
        if (i < m) { ss[i] = listScore[c * CAP + i]; si[i] = listIdx[c * CAP + i]; }
        else       { ss[i] = -INFINITY;              si[i] = 0x7FFFFFFF; }
    }
    __syncthreads();

    for (int size = 2; size <= P; size <<= 1) {
        for (int stride = size >> 1; stride > 0; stride >>= 1) {
            for (int t = lane; t < P / 2; t += 64) {
                int lo = 2 * stride * (t / stride) + (t % stride);
                int hi = lo + stride;
                bool desc = ((lo & size) == 0);
                float slo = ss[lo], shi = ss[hi];
                int   ilo = si[lo], ihi = si[hi];
                bool loBetter = (slo > shi) || (slo == shi && ilo < ihi);
                bool doSwap = desc ? !loBetter : loBetter;
                if (doSwap) { ss[lo] = shi; ss[hi] = slo; si[lo] = ihi; si[hi] = ilo; }
            }
            __syncthreads();
        }
    }

    // gather candidates into registers (4 slots/lane)
    float cx1[4], cy1[4], cx2[4], cy2[4], car[4];
    int   cidx[4];
    bool  cval[4];
#pragma unroll
    for (int s = 0; s < 4; s++) {
        int j = s * 64 + lane;
        cval[s] = (j < m);
        cidx[s] = 0;
        cx1[s] = 0.f; cy1[s] = 0.f; cx2[s] = 0.f; cy2[s] = 0.f; car[s] = 0.f;
        if (cval[s]) {
            int n = si[j];
            cidx[s] = n;
            float4 b = nmsBox[n];
            cx1[s] = b.x; cy1[s] = b.y; cx2[s] = b.z; cy2[s] = b.w;
            car[s] = nmsArea[n];
        }
    }

    // greedy: chunked by pivot slot (compile-time), readlane broadcasts
    int sp = 0;
#pragma unroll
    for (int s0 = 0; s0 < 4; s0++) {
        const int kend = (m < (s0 + 1) * 64) ? m : (s0 + 1) * 64;
        for (int k = s0 * 64; k < kend; k++) {
            const int owner = k & 63;                       // SGPR-uniform
            int pk = __builtin_amdgcn_readlane(sp, owner);
            if ((pk >> s0) & 1) continue;                   // pivot suppressed

            float px1 = rlanef(cx1[s0], owner);
            float py1 = rlanef(cy1[s0], owner);
            float px2 = rlanef(cx2[s0], owner);
            float py2 = rlanef(cy2[s0], owner);
            float pa  = rlanef(car[s0], owner);

#pragma unroll
            for (int s = s0; s < 4; s++) {
                int j = s * 64 + lane;
                if (j > k && j < m) {
                    float xx1 = fmaxf(px1, cx1[s]);
                    float yy1 = fmaxf(py1, cy1[s]);
                    float xx2 = fminf(px2, cx2[s]);
                    float yy2 = fminf(py2, cy2[s]);
                    float inter = fmaxf(1e-10f, xx2 - xx1) * fmaxf(1e-10f, yy2 - yy1);
                    float iou = inter / ((pa + car[s] - inter) + 1e-14f);
                    if (iou > 0.5f) sp |= (1 << s);
                }
            }
        }
    }

    // scatter keep bits
#pragma unroll
    for (int s = 0; s < 4; s++) {
        if (cval[s] && !((sp >> s) & 1)) keepOut[cidx[s]] = 1.0f;
    }
}

// ---------------------------------------------------------------------------
extern "C" void kernel_launch(void* const* d_in, const int* in_sizes, int n_in,
                              void* d_out, int out_size, void* d_ws, size_t ws_size,
                              hipStream_t stream) {
    const float* cls_feat = (const float*)d_in[0];
    const float* reg_feat = (const float*)d_in[1];
    const float* w_obj    = (const float*)d_in[2];
    const float* b_obj    = (const float*)d_in[3];
    const float* w_cls    = (const float*)d_in[4];
    const float* b_cls    = (const float*)d_in[5];
    const float* w_reg    = (const float*)d_in[6];
    const float* b_reg    = (const float*)d_in[7];

    float* out = (float*)d_out;
    float* ws  = (float*)d_ws;

    // workspace layout (floats)
    float*  clsRaw    = ws;                       // 640000
    float*  roRaw     = ws + 640000;              // 40000
    float4* nmsBox    = (float4*)(ws + 680000);   // 32000 floats (16B-aligned offset)
    float*  nmsArea   = ws + 712000;              // 8000
    float*  listScore = ws + 720000;              // 80*256 = 20480
    int*    listIdx   = (int*)(ws + 740480);      // 80*256
    int*    counts    = (int*)(ws + 760960);      // 80
    // total ~3.05 MB

    k_gemm<<<dim3(13, 107), 64, 0, stream>>>(cls_feat, reg_feat,
                                             w_obj, b_obj, w_cls, b_cls, w_reg, b_reg,
                                             clsRaw, roRaw, counts);
    k_box<<<NBOX / 4, 256, 0, stream>>>(clsRaw, roRaw, out, nmsBox, nmsArea,
                                        listScore, listIdx, counts);
    k_nms<<<NCLS, 64, 0, stream>>>(listScore, listIdx, counts, nmsBox, nmsArea,
                                   out + 48000);
}

// Round 10
// 173.715 us; speedup vs baseline: 1.1218x; 1.1218x over previous
//
#include <hip/hip_runtime.h>
#include <math.h>

#define FMPX 40
#define NPOS 1600          // 40*40
#define NCLS 80
#define NBOX 8000
#define KDIM 512
#define CAP  256           // per-class candidate capacity (mean ~100/class, +15 sigma)

// anchor (w,h) pairs
__constant__ float c_aw[5] = {17.f, 55.f, 92.f, 202.f, 289.f};
__constant__ float c_ah[5] = {25.f, 75.f, 206.f, 21.f, 311.f};

__device__ __forceinline__ float sigf(float x) { return 1.0f / (1.0f + expf(-x)); }
__device__ __forceinline__ float rlanef(float v, int lane) {
    return __uint_as_float(__builtin_amdgcn_readlane(__float_as_uint(v), lane));
}

// ---------------------------------------------------------------------------
// K1: the three 1x1-conv GEMMs. M=128/wave (2 pos/lane), N=2 outs/wave.
// R9 lesson: 48-deep prefetch doubled FETCH (L2 reuse-distance blowout ->
// HBM misses) at 7% occupancy — reverted to R7's 16k lookahead. Occupancy is
// THE lever and wave count = 680K/(M*N): N=2 doubles waves to 2769 (10.8/CU,
// 2.7/SIMD) while keeping the per-wave VALU:LDS ratio VALU-bound
// (32cyc FMA per 24cyc W-b128 per 8k). Pipe floors/CU: LDS 14us, VALU 18us,
// L2 ~21us. Scalar pipe for per-step W stays DEAD (R4/R6). K CANNOT be split
// across waves: per-output FMA order must remain ascending k 0..511
// (argmax near-tie protection; absmax exactly 2.0 for 9 rounds).
// grid = (13 M-tiles of 128 pos, 213 N-tiles of 2 outs):
//   nTile 0..199: cls outs oBase=nTile*2 (cls_feat);
//   nTile 200..212: ro outs oBase=(nTile-200)*2 (reg_feat; last has 1 pad).
// Block (0,0) zeroes counts[] for k_box's atomic list build.
// ---------------------------------------------------------------------------
__global__ __launch_bounds__(64) void k_gemm(
    const float* __restrict__ cls_feat, const float* __restrict__ reg_feat,
    const float* __restrict__ w_obj, const float* __restrict__ b_obj,
    const float* __restrict__ w_cls, const float* __restrict__ b_cls,
    const float* __restrict__ w_reg, const float* __restrict__ b_reg,
    float* __restrict__ clsRaw,   // [1600][400]
    float* __restrict__ roRaw,    // [1600][25]: 0..4 obj, 5..24 reg
    int* __restrict__ counts)     // [80] zeroed here for k_box
{
    __shared__ float Ws[2 * KDIM];         // 4 KB
    const int mTile = blockIdx.x;          // 0..12
    const int nTile = blockIdx.y;          // 0..212
    const int hw0   = mTile * 128;
    const bool isCls = (nTile < 200);
    const float* feat = isCls ? cls_feat : reg_feat;
    const int lane = threadIdx.x;
    const int oBase = isCls ? nTile * 2 : (nTile - 200) * 2;

    if (mTile == 0 && nTile == 0) {
        counts[lane] = 0;                       // lanes 0..63
        if (lane < NCLS - 64) counts[64 + lane] = 0;
    }

    // ---- stage W tile [2][512] (4 float4 per lane, coalesced) ----
    for (int i = lane * 4; i < 2 * KDIM; i += 64 * 4) {
        int r = i >> 9, k = i & 511;
        const float* src;
        bool valid = true;
        if (isCls) {
            src = w_cls + (oBase + r) * KDIM + k;
        } else {
            int o = oBase + r;
            if (o < 5)       src = w_obj + o * KDIM + k;
            else if (o < 25) src = w_reg + (o - 5) * KDIM + k;
            else           { src = w_obj; valid = false; }
        }
        float4 v = valid ? *(const float4*)src : make_float4(0.f, 0.f, 0.f, 0.f);
        *(float4*)&Ws[i] = v;
    }

    float bias[2];
    bool ok[2];
#pragma unroll
    for (int j = 0; j < 2; j++) {
        int o = oBase + j;
        if (isCls)      { bias[j] = b_cls[o];     ok[j] = true; }
        else if (o < 5) { bias[j] = b_obj[o];     ok[j] = true; }
        else if (o < 25){ bias[j] = b_reg[o - 5]; ok[j] = true; }
        else            { bias[j] = 0.0f;         ok[j] = false; }
    }

    // two positions per lane; pos1 invalid only in the last M-tile (hw>=1600)
    const bool ok1 = (hw0 + 64 + lane) < NPOS;
    const float* apa = feat + hw0 + lane;
    const float* apb = feat + (ok1 ? hw0 + 64 + lane : hw0 + lane);

    // A register double buffer, 16k lookahead (R7's measured-good depth)
    float A0a[8], A0b[8], A1a[8], A1b[8];
#pragma unroll
    for (int t = 0; t < 8; t++) { A0a[t] = apa[t * NPOS];       A0b[t] = apb[t * NPOS]; }
#pragma unroll
    for (int t = 0; t < 8; t++) { A1a[t] = apa[(8 + t) * NPOS]; A1b[t] = apb[(8 + t) * NPOS]; }

    __syncthreads();   // single-wave block: effectively a waitcnt

    float acc[2] = {0.f, 0.f};
    float acd[2] = {0.f, 0.f};

    for (int kk = 0; kk < KDIM - 16; kk += 16) {
#pragma unroll
        for (int j = 0; j < 2; j++) {
            const float* wp = &Ws[j * KDIM + kk];      // LDS b128 x2, broadcast
#pragma unroll
            for (int t = 0; t < 8; t++) {
                acc[j] += A0a[t] * wp[t];
                acd[j] += A0b[t] * wp[t];
            }
        }
#pragma unroll
        for (int t = 0; t < 8; t++) { A0a[t] = apa[(kk + 16 + t) * NPOS]; A0b[t] = apb[(kk + 16 + t) * NPOS]; }
#pragma unroll
        for (int j = 0; j < 2; j++) {
            const float* wp = &Ws[j * KDIM + kk + 8];
#pragma unroll
            for (int t = 0; t < 8; t++) {
                acc[j] += A1a[t] * wp[t];
                acd[j] += A1b[t] * wp[t];
            }
        }
#pragma unroll
        for (int t = 0; t < 8; t++) { A1a[t] = apa[(kk + 24 + t) * NPOS]; A1b[t] = apb[(kk + 24 + t) * NPOS]; }
    }
    {   // tail: k = 496..511
        const int kk = KDIM - 16;
#pragma unroll
        for (int j = 0; j < 2; j++) {
            const float* wp = &Ws[j * KDIM + kk];
#pragma unroll
            for (int t = 0; t < 8; t++) {
                acc[j] += A0a[t] * wp[t];
                acd[j] += A0b[t] * wp[t];
            }
        }
#pragma unroll
        for (int j = 0; j < 2; j++) {
            const float* wp = &Ws[j * KDIM + kk + 8];
#pragma unroll
            for (int t = 0; t < 8; t++) {
                acc[j] += A1a[t] * wp[t];
                acd[j] += A1b[t] * wp[t];
            }
        }
    }

    const int hw  = hw0 + lane;
    const int hw2 = hw + 64;
    if (isCls) {
        *(float2*)&clsRaw[hw * 400 + oBase] = make_float2(acc[0] + bias[0], acc[1] + bias[1]);
        if (ok1)
            *(float2*)&clsRaw[hw2 * 400 + oBase] = make_float2(acd[0] + bias[0], acd[1] + bias[1]);
    } else {
#pragma unroll
        for (int j = 0; j < 2; j++) {
            int o = oBase + j;
            if (ok[j]) {
                roRaw[hw * 25 + o] = acc[j] + bias[j];
                if (ok1) roRaw[hw2 * 25 + o] = acd[j] + bias[j];
            }
        }
    }
}

// ---------------------------------------------------------------------------
// K2: per-box scores, argmax label, decode, outputs, per-class candidate
// append (one global atomicAdd per box on lane 0; compaction order is
// irrelevant — k_nms's (score desc, idx asc) sort is deterministic ==
// stable argsort(-score) restricted to the class).  (unchanged from R9)
// ---------------------------------------------------------------------------
__global__ __launch_bounds__(256) void k_box(
    const float* __restrict__ clsRaw, const float* __restrict__ roRaw,
    float* __restrict__ out,          // d_out: [32000 bboxes][8000 score][8000 labels][8000 keep]
    float4* __restrict__ nmsBox, float* __restrict__ nmsArea,
    float* __restrict__ listScore, int* __restrict__ listIdx, int* __restrict__ counts)
{
    const int n = blockIdx.x * 4 + (threadIdx.x >> 6);   // box index 0..7999
    const int lane = threadIdx.x & 63;
    const int hw = n / 5, a = n % 5;

    const float sobj = sigf(roRaw[hw * 25 + a]);
    const float* cbase = clsRaw + hw * 400 + a * 80;

    const int l4 = (lane < 20) ? lane : 19;     // clamp for safe address
    float4 cs = *(const float4*)(cbase + l4 * 4);

    // in-lane first-max over classes l4*4..l4*4+3 (strict > keeps first)
    float s0 = sqrtf(sobj * sigf(cs.x));
    float s1 = sqrtf(sobj * sigf(cs.y));
    float s2 = sqrtf(sobj * sigf(cs.z));
    float s3 = sqrtf(sobj * sigf(cs.w));
    float v = s0; int bi = l4 * 4;
    if (s1 > v) { v = s1; bi = l4 * 4 + 1; }
    if (s2 > v) { v = s2; bi = l4 * 4 + 2; }
    if (s3 > v) { v = s3; bi = l4 * 4 + 3; }
    if (lane >= 20) { v = -1.0f; bi = 0x7FFFFFFF; }  // scores are always > 0

    // cross-lane: max score, ties -> lowest class (== jnp.argmax first-max)
#pragma unroll
    for (int off = 32; off >= 1; off >>= 1) {
        float ov = __shfl_xor(v, off);
        int   oi = __shfl_xor(bi, off);
        if (ov > v || (ov == v && oi < bi)) { v = ov; bi = oi; }
    }

    if (lane == 0) {
        const float* rp = roRaw + hw * 25 + 5 + a * 4;
        float r0 = rp[0], r1 = rp[1], r2 = rp[2], r3 = rp[3];
        float gx = (float)(hw % FMPX), gy = (float)(hw / FMPX);
        float cx = (sigf(r0) + gx) * 32.0f;
        float cy = (sigf(r1) + gy) * 32.0f;
        float wv = expf(r2) * c_aw[a];
        float hv = expf(r3) * c_ah[a];
        float x1 = cx - wv * 0.5f, y1 = cy - hv * 0.5f;
        float x2 = cx + wv * 0.5f, y2 = cy + hv * 0.5f;

        *(float4*)&out[n * 4] = make_float4(x1, y1, x2, y2);
        out[32000 + n] = v;
        out[40000 + n] = (float)bi;
        out[48000 + n] = 0.0f;            // keep init (k_nms sets 1s later)

        // b2: reinterpret x1y1x2y2 as cxcywh (faithful to the reference nms())
        float nx1 = x1 - x2 * 0.5f, ny1 = y1 - y2 * 0.5f;
        float nx2 = x1 + x2 * 0.5f, ny2 = y1 + y2 * 0.5f;
        nmsBox[n]  = make_float4(nx1, ny1, nx2, ny2);
        nmsArea[n] = (nx2 - nx1) * (ny2 - ny1);

        if (v >= 0.3f) {
            int p = atomicAdd(&counts[bi], 1);
            if (p < CAP) { listScore[bi * CAP + p] = v; listIdx[bi * CAP + p] = n; }
        }
    }
}

// ---------------------------------------------------------------------------
// K3: per-class greedy NMS — one wave per class, pre-compacted lists (no
// scan), bitonic sort by (score desc, idx asc), register-resident greedy
// with v_readlane broadcasts.  (unchanged from R9)
// ---------------------------------------------------------------------------
__global__ __launch_bounds__(64) void k_nms(
    const float* __restrict__ listScore, const int* __restrict__ listIdx,
    const int* __restrict__ counts,
    const float4* __restrict__ nmsBox, const float* __restrict__ nmsArea,
    float* __restrict__ keepOut)
{
    const int c = blockIdx.x;
    const int lane = threadIdx.x;

    __shared__ float ss[CAP];
    __shared__ int   si[CAP];

    int m = counts[c];
    if (m > CAP) m = CAP;

    int P = 2;
    while (P < m) P <<= 1;
    for (int i = lane; i < P; i += 64) {
        if (i < m) { ss[i] = listScore[c * CAP + i]; si[i] = listIdx[c * CAP + i]; }
        else       { ss[i] = -INFINITY;              si[i] = 0x7FFFFFFF; }
    }
    __syncthreads();

    for (int size = 2; size <= P; size <<= 1) {
        for (int stride = size >> 1; stride > 0; stride >>= 1) {
            for (int t = lane; t < P / 2; t += 64) {
                int lo = 2 * stride * (t / stride) + (t % stride);
                int hi = lo + stride;
                bool desc = ((lo & size) == 0);
                float slo = ss[lo], shi = ss[hi];
                int   ilo = si[lo], ihi = si[hi];
                bool loBetter = (slo > shi) || (slo == shi && ilo < ihi);
                bool doSwap = desc ? !loBetter : loBetter;
                if (doSwap) { ss[lo] = shi; ss[hi] = slo; si[lo] = ihi; si[hi] = ilo; }
            }
            __syncthreads();
        }
    }

    // gather candidates into registers (4 slots/lane)
    float cx1[4], cy1[4], cx2[4], cy2[4], car[4];
    int   cidx[4];
    bool  cval[4];
#pragma unroll
    for (int s = 0; s < 4; s++) {
        int j = s * 64 + lane;
        cval[s] = (j < m);
        cidx[s] = 0;
        cx1[s] = 0.f; cy1[s] = 0.f; cx2[s] = 0.f; cy2[s] = 0.f; car[s] = 0.f;
        if (cval[s]) {
            int n = si[j];
            cidx[s] = n;
            float4 b = nmsBox[n];
            cx1[s] = b.x; cy1[s] = b.y; cx2[s] = b.z; cy2[s] = b.w;
            car[s] = nmsArea[n];
        }
    }

    // greedy: chunked by pivot slot (compile-time), readlane broadcasts
    int sp = 0;
#pragma unroll
    for (int s0 = 0; s0 < 4; s0++) {
        const int kend = (m < (s0 + 1) * 64) ? m : (s0 + 1) * 64;
        for (int k = s0 * 64; k < kend; k++) {
            const int owner = k & 63;                       // SGPR-uniform
            int pk = __builtin_amdgcn_readlane(sp, owner);
            if ((pk >> s0) & 1) continue;                   // pivot suppressed

            float px1 = rlanef(cx1[s0], owner);
            float py1 = rlanef(cy1[s0], owner);
            float px2 = rlanef(cx2[s0], owner);
            float py2 = rlanef(cy2[s0], owner);
            float pa  = rlanef(car[s0], owner);

#pragma unroll
            for (int s = s0; s < 4; s++) {
                int j = s * 64 + lane;
                if (j > k && j < m) {
                    float xx1 = fmaxf(px1, cx1[s]);
                    float yy1 = fmaxf(py1, cy1[s]);
                    float xx2 = fminf(px2, cx2[s]);
                    float yy2 = fminf(py2, cy2[s]);
                    float inter = fmaxf(1e-10f, xx2 - xx1) * fmaxf(1e-10f, yy2 - yy1);
                    float iou = inter / ((pa + car[s] - inter) + 1e-14f);
                    if (iou > 0.5f) sp |= (1 << s);
                }
            }
        }
    }

    // scatter keep bits
#pragma unroll
    for (int s = 0; s < 4; s++) {
        if (cval[s] && !((sp >> s) & 1)) keepOut[cidx[s]] = 1.0f;
    }
}

// ---------------------------------------------------------------------------
extern "C" void kernel_launch(void* const* d_in, const int* in_sizes, int n_in,
                              void* d_out, int out_size, void* d_ws, size_t ws_size,
                              hipStream_t stream) {
    const float* cls_feat = (const float*)d_in[0];
    const float* reg_feat = (const float*)d_in[1];
    const float* w_obj    = (const float*)d_in[2];
    const float* b_obj    = (const float*)d_in[3];
    const float* w_cls    = (const float*)d_in[4];
    const float* b_cls    = (const float*)d_in[5];
    const float* w_reg    = (const float*)d_in[6];
    const float* b_reg    = (const float*)d_in[7];

    float* out = (float*)d_out;
    float* ws  = (float*)d_ws;

    // workspace layout (floats)
    float*  clsRaw    = ws;                       // 640000
    float*  roRaw     = ws + 640000;              // 40000
    float4* nmsBox    = (float4*)(ws + 680000);   // 32000 floats (16B-aligned offset)
    float*  nmsArea   = ws + 712000;              // 8000
    float*  listScore = ws + 720000;              // 80*256 = 20480
    int*    listIdx   = (int*)(ws + 740480);      // 80*256
    int*    counts    = (int*)(ws + 760960);      // 80
    // total ~3.05 MB

    k_gemm<<<dim3(13, 213), 64, 0, stream>>>(cls_feat, reg_feat,
                                             w_obj, b_obj, w_cls, b_cls, w_reg, b_reg,
                                             clsRaw, roRaw, counts);
    k_box<<<NBOX / 4, 256, 0, stream>>>(clsRaw, roRaw, out, nmsBox, nmsArea,
                                        listScore, listIdx, counts);
    k_nms<<<NCLS, 64, 0, stream>>>(listScore, listIdx, counts, nmsBox, nmsArea,
                                   out + 48000);
}